// Round 6
// baseline (475.900 us; speedup 1.0000x reference)
//
#include <hip/hip_runtime.h>
#include <hip/hip_bf16.h>

#define B 8
#define N 8192
#define E 65536
#define FIN 64
#define H 128
#define OUTD 256
#define NLAYER 3
#define EPS 1e-5f
#define PCHUNK 64
#define PNODES (N / PCHUNK)
#define TM 32
#define PADF 68
#define NNODE (B * N)            // 65536 rows
#define KSTEPS 20                // 5 groups x 4 k-steps of K=32
#define BPL (KSTEPS * 8 * 512)   // Bp ushort elems per layer

typedef float f32x4 __attribute__((ext_vector_type(4)));
typedef __bf16 bf16x8 __attribute__((ext_vector_type(8)));

__device__ __forceinline__ float b2f(unsigned short u) {
    union { float f; unsigned int i; } c; c.i = ((unsigned int)u) << 16; return c.f;
}
__device__ __forceinline__ unsigned short f2b(float f) {
    __hip_bfloat16 h = __float2bfloat16(f);          // RTNE
    return *reinterpret_cast<unsigned short*>(&h);
}

// ---------------- weight pre-pack: fragment-ordered split-bf16 B' ----------------
// groups: 0 xh*sWhi, 1 xl*sWhi, 2 xh*sWlo, 3 nh*nWhi, 4 nh*nWlo
__global__ void k_prepB(const float* __restrict__ selfW, const float* __restrict__ neighW,
                        unsigned short* __restrict__ Bp) {
    const int idx = blockIdx.x;            // l*KSTEPS*8 + s*8 + t
    const int t = idx & 7;
    const int s = (idx >> 3) % KSTEPS;
    const int l = idx / (KSTEPS * 8);
    const int lane = threadIdx.x;
    const int quad = lane >> 4, col = lane & 15;
    const int g = s >> 2;
    const float* W = ((g < 3) ? selfW : neighW) + (size_t)l * H * H;
    const bool lo = (g == 2 || g == 4);
    const int n = t * 16 + col;
    unsigned short* dst = Bp + ((size_t)(l * KSTEPS + s) * 8 + t) * 512 + lane * 8;
    #pragma unroll
    for (int j = 0; j < 8; ++j) {
        const int kk = (s & 3) * 32 + quad * 8 + j;
        const float w = W[kk * H + n];
        const unsigned short hi = f2b(w);
        dst[j] = lo ? f2b(w - b2f(hi)) : hi;
    }
}

// ---------------- input projection -> split-bf16 x ----------------
__global__ __launch_bounds__(256) void k_inproj3(const float* __restrict__ feats,
                                                 const float* __restrict__ W,
                                                 const float* __restrict__ bias,
                                                 unsigned short* __restrict__ xh,
                                                 unsigned short* __restrict__ xl) {
    __shared__ float fs[TM * PADF];
    __shared__ float wB[FIN * H];
    const int tid = threadIdx.x;
    const int i = tid >> 5, j = tid & 31;
    const int row0 = blockIdx.x * TM;

    for (int v = tid; v < TM * (FIN / 4); v += 256) {
        int n = v >> 4, kq = (v & 15) << 2;
        *(float4*)&fs[n * PADF + kq] = *(const float4*)&feats[(size_t)(row0 + n) * FIN + kq];
    }
    for (int v = tid; v < FIN * H / 4; v += 256)
        *(float4*)&wB[v * 4] = *(const float4*)&W[v * 4];
    __syncthreads();

    float acc[4][4] = {};
    #pragma unroll
    for (int k4 = 0; k4 < FIN / 4; ++k4) {
        float4 xa[4];
        #pragma unroll
        for (int a = 0; a < 4; ++a)
            xa[a] = *(const float4*)&fs[(i * 4 + a) * PADF + k4 * 4];
        #pragma unroll
        for (int t = 0; t < 4; ++t) {
            float4 bs = *(const float4*)&wB[(k4 * 4 + t) * H + (j << 2)];
            #pragma unroll
            for (int a = 0; a < 4; ++a) {
                const float va = ((const float*)&xa[a])[t];
                acc[a][0] = fmaf(va, bs.x, acc[a][0]);
                acc[a][1] = fmaf(va, bs.y, acc[a][1]);
                acc[a][2] = fmaf(va, bs.z, acc[a][2]);
                acc[a][3] = fmaf(va, bs.w, acc[a][3]);
            }
        }
    }
    const float4 bv = *(const float4*)&bias[j << 2];
    #pragma unroll
    for (int a = 0; a < 4; ++a) {
        float o[4];
        o[0] = fmaxf(acc[a][0] + bv.x, 0.f);
        o[1] = fmaxf(acc[a][1] + bv.y, 0.f);
        o[2] = fmaxf(acc[a][2] + bv.z, 0.f);
        o[3] = fmaxf(acc[a][3] + bv.w, 0.f);
        ushort4 h4, l4;
        h4.x = f2b(o[0]); l4.x = f2b(o[0] - b2f(h4.x));
        h4.y = f2b(o[1]); l4.y = f2b(o[1] - b2f(h4.y));
        h4.z = f2b(o[2]); l4.z = f2b(o[2] - b2f(h4.z));
        h4.w = f2b(o[3]); l4.w = f2b(o[3] - b2f(h4.w));
        const size_t a0 = (size_t)(row0 + i * 4 + a) * H + (j << 2);
        *(ushort4*)&xh[a0] = h4;
        *(ushort4*)&xl[a0] = l4;
    }
}

// ---------------- CSR build ----------------
__global__ void k_count(const int* __restrict__ ei, const float* __restrict__ emask,
                        int* __restrict__ cnt_i) {
    const int ge = blockIdx.x * 256 + threadIdx.x;
    if (emask[ge] > 0.f) {
        const int b = ge >> 16, e = ge & 0xFFFF;
        const int tgt = ei[(b * 2 + 1) * E + e];
        atomicAdd(&cnt_i[b * N + tgt], 1);
    }
}

__global__ __launch_bounds__(1024) void k_scan(const int* __restrict__ cnt_i,
                                               int* __restrict__ off, int* __restrict__ cur) {
    __shared__ int part[1024];
    const int t = threadIdx.x;
    const int base = t * 64;
    int s = 0;
    const int4* c4 = (const int4*)(cnt_i + base);
    #pragma unroll
    for (int u = 0; u < 16; ++u) {
        const int4 v = c4[u];
        s += v.x + v.y + v.z + v.w;
    }
    part[t] = s;
    __syncthreads();
    for (int d = 1; d < 1024; d <<= 1) {
        int v = (t >= d) ? part[t - d] : 0;
        __syncthreads();
        part[t] += v;
        __syncthreads();
    }
    int pre = (t == 0) ? 0 : part[t - 1];
    for (int u = 0; u < 64; ++u) {
        const int c = cnt_i[base + u];
        off[base + u] = pre;
        cur[base + u] = pre;
        pre += c;
    }
    if (t == 1023) off[NNODE] = pre;
}

__global__ void k_fill(const int* __restrict__ ei, const float* __restrict__ emask,
                       int* __restrict__ cur, int* __restrict__ esrc, float* __restrict__ emv) {
    const int ge = blockIdx.x * 256 + threadIdx.x;
    const float m = emask[ge];
    if (m > 0.f) {
        const int b = ge >> 16, e = ge & 0xFFFF;
        const int tgt = ei[(b * 2 + 1) * E + e];
        const int src = ei[(b * 2) * E + e];
        const int p = atomicAdd(&cur[b * N + tgt], 1);
        esrc[p] = b * N + src;
        emv[p] = m;
    }
}

// ---------------- gather: mean over incoming edges, bf16-hi input, wave-per-row ----------------
__global__ __launch_bounds__(256) void k_gather3(const unsigned int* __restrict__ xh32,
                                                 const int* __restrict__ off,
                                                 const int* __restrict__ esrc,
                                                 const float* __restrict__ emv,
                                                 unsigned int* __restrict__ nh32) {
    const int beta = blockIdx.x;               // 0..16383
    const int b = beta & 7;
    const int grp = beta >> 3;                 // 0..2047
    const int wave = threadIdx.x >> 6, lane = threadIdx.x & 63;
    const int r = b * N + grp * 4 + wave;
    const int j0 = off[r], j1 = off[r + 1];
    float a0 = 0.f, a1 = 0.f, c = 0.f;
    for (int base = j0; base < j1; base += 64) {
        const int myj = base + lane;
        int s_l = 0; float m_l = 0.f;
        if (myj < j1) { s_l = esrc[myj]; m_l = emv[myj]; }
        const int cnt = min(64, j1 - base);
        #pragma unroll 4
        for (int jj = 0; jj < cnt; ++jj) {
            const int src = __shfl(s_l, jj);
            const float m = __shfl(m_l, jj);
            const unsigned int u = xh32[(size_t)src * 64 + lane];
            union { unsigned int i; float f; } lo, hi;
            lo.i = u << 16;
            hi.i = u & 0xFFFF0000u;
            a0 = fmaf(lo.f, m, a0);
            a1 = fmaf(hi.f, m, a1);
            c += m;
        }
    }
    const float inv = 1.f / fmaxf(c, 1.f);
    nh32[(size_t)r * 64 + lane] = (unsigned int)f2b(a0 * inv) | ((unsigned int)f2b(a1 * inv) << 16);
}

// ---------------- fused layer v4: 32 rows/block, 2048 blocks, prefetch pipeline ----------------
// wave (mw,nw): m-tile mw (16 rows), n-tiles nw*4..nw*4+3 (64 cols). acc = 4 x f32x4.
// In-place safe: block reads/writes only rows [row0, row0+32).
__global__ __launch_bounds__(256) void k_layer4(const unsigned short* __restrict__ xh,
                                                const unsigned short* __restrict__ xl,
                                                const unsigned short* __restrict__ nh,
                                                const unsigned short* __restrict__ Bp,
                                                const float* __restrict__ sb,
                                                const float* __restrict__ nb,
                                                const float* __restrict__ lng,
                                                const float* __restrict__ lnb,
                                                const float* __restrict__ nmask,
                                                unsigned short* __restrict__ oxh,
                                                unsigned short* __restrict__ oxl) {
    const int tid = threadIdx.x;
    const int wave = tid >> 6, lane = tid & 63;
    const int quad = lane >> 4, col = lane & 15;
    const int mw = wave >> 1, nw = wave & 1;
    const int row0 = blockIdx.x * 32;
    const int myrow = row0 + mw * 16 + col;        // A row this lane feeds
    const size_t abase = (size_t)myrow * H + quad * 8;

    f32x4 acc[4] = {};

    // prefetch step 0 (group 0 = xh)
    bf16x8 aC = *(const bf16x8*)&xh[abase];
    bf16x8 bC[4];
    #pragma unroll
    for (int nt = 0; nt < 4; ++nt)
        bC[nt] = *(const bf16x8*)&Bp[((size_t)(nw * 4 + nt)) * 512 + lane * 8];

    #pragma unroll 4
    for (int s = 0; s < KSTEPS; ++s) {
        bf16x8 aN, bN[4];
        if (s + 1 < KSTEPS) {
            const int s1 = s + 1, g1 = s1 >> 2;
            const unsigned short* A = (g1 == 0 || g1 == 2) ? xh : (g1 == 1) ? xl : nh;
            aN = *(const bf16x8*)&A[abase + (s1 & 3) * 32];
            #pragma unroll
            for (int nt = 0; nt < 4; ++nt)
                bN[nt] = *(const bf16x8*)&Bp[((size_t)s1 * 8 + nw * 4 + nt) * 512 + lane * 8];
        }
        #pragma unroll
        for (int nt = 0; nt < 4; ++nt)
            acc[nt] = __builtin_amdgcn_mfma_f32_16x16x32_bf16(aC, bC[nt], acc[nt], 0, 0, 0);
        aC = aN;
        #pragma unroll
        for (int nt = 0; nt < 4; ++nt) bC[nt] = bN[nt];
    }

    // bias + relu (C/D layout: row = quad*4 + r, col = lane&15; h = (nw*4+nt)*16 + col)
    float sbv[4], nbv[4], gv[4], bbv[4];
    #pragma unroll
    for (int nt = 0; nt < 4; ++nt) {
        const int hh = (nw * 4 + nt) * 16 + col;
        sbv[nt] = sb[hh]; nbv[nt] = nb[hh]; gv[nt] = lng[hh]; bbv[nt] = lnb[hh];
    }
    #pragma unroll
    for (int nt = 0; nt < 4; ++nt)
        #pragma unroll
        for (int r = 0; r < 4; ++r)
            acc[nt][r] = fmaxf(acc[nt][r] + sbv[nt] + nbv[nt], 0.f);

    // LN partials: wave covers 64 of 128 h for its 16 rows
    __shared__ float lsum[2][32];
    __shared__ float lsq[2][32];
    #pragma unroll
    for (int r = 0; r < 4; ++r) {
        float p = 0.f, q = 0.f;
        #pragma unroll
        for (int nt = 0; nt < 4; ++nt) {
            const float v = acc[nt][r];
            p += v;
            q = fmaf(v, v, q);
        }
        p += __shfl_xor(p, 1);  q += __shfl_xor(q, 1);
        p += __shfl_xor(p, 2);  q += __shfl_xor(q, 2);
        p += __shfl_xor(p, 4);  q += __shfl_xor(q, 4);
        p += __shfl_xor(p, 8);  q += __shfl_xor(q, 8);
        if (col == 0) {
            const int rib = mw * 16 + quad * 4 + r;
            lsum[nw][rib] = p;
            lsq[nw][rib] = q;
        }
    }
    __syncthreads();

    #pragma unroll
    for (int r = 0; r < 4; ++r) {
        const int rib = mw * 16 + quad * 4 + r;
        const int node = row0 + rib;
        const float mu = (lsum[0][rib] + lsum[1][rib]) * (1.f / H);
        const float var = (lsq[0][rib] + lsq[1][rib]) * (1.f / H) - mu * mu;
        const float isd = rsqrtf(var + EPS);
        const float m = nmask[node];
        #pragma unroll
        for (int nt = 0; nt < 4; ++nt) {
            const float y = (fmaf(acc[nt][r] - mu, isd * gv[nt], bbv[nt])) * m;
            const unsigned short hi = f2b(y);
            const size_t a = (size_t)node * H + (nw * 4 + nt) * 16 + col;
            oxh[a] = hi;
            oxl[a] = f2b(y - b2f(hi));
        }
    }
}

// ---------------- pooling partials ----------------
__global__ void k_pool1(const unsigned short* __restrict__ xh,
                        const unsigned short* __restrict__ xl,
                        const float* __restrict__ nmask, float* __restrict__ part) {
    const int b = blockIdx.x, c = blockIdx.y, h = threadIdx.x;
    const int n0 = c * PNODES;
    float s = 0.f, mx = -INFINITY, nv = 0.f;
    for (int it = 0; it < PNODES; ++it) {
        const int n = n0 + it;
        const float m = nmask[b * N + n];
        const size_t a = ((size_t)b * N + n) * H + h;
        const float v = (b2f(xh[a]) + b2f(xl[a])) * m;
        s += v;
        if (m > 0.f) mx = fmaxf(mx, v);
        nv += m;
    }
    float* p = part + ((size_t)b * PCHUNK + c) * (2 * H + 1);
    p[h] = s;
    p[H + h] = mx;
    if (h == 0) p[2 * H] = nv;
}

// ---------------- fused pool-reduce + MLP head ----------------
__global__ __launch_bounds__(256) void k_tail(const float* __restrict__ part,
                                              const float* __restrict__ W1, const float* __restrict__ b1,
                                              const float* __restrict__ W2, const float* __restrict__ b2,
                                              float* __restrict__ out) {
    const int b = blockIdx.x, t = threadIdx.x;
    __shared__ float g[2 * H];
    __shared__ float hid[H];
    {
        float nv = 0.f;
        for (int c = 0; c < PCHUNK; ++c)
            nv += part[((size_t)b * PCHUNK + c) * (2 * H + 1) + 2 * H];
        if (t < H) {
            float s = 0.f;
            for (int c = 0; c < PCHUNK; ++c)
                s += part[((size_t)b * PCHUNK + c) * (2 * H + 1) + t];
            g[t] = s / fmaxf(nv, 1.f);
        } else {
            const int h = t - H;
            float mx = -INFINITY;
            for (int c = 0; c < PCHUNK; ++c)
                mx = fmaxf(mx, part[((size_t)b * PCHUNK + c) * (2 * H + 1) + H + h]);
            g[t] = mx;
        }
    }
    __syncthreads();
    if (t < H) {
        float a = b1[t];
        #pragma unroll 8
        for (int k = 0; k < 2 * H; ++k) a = fmaf(g[k], W1[k * H + t], a);
        hid[t] = fmaxf(a, 0.f);
    }
    __syncthreads();
    float a = b2[t];
    #pragma unroll 8
    for (int k = 0; k < H; ++k) a = fmaf(hid[k], W2[k * OUTD + t], a);
    out[(size_t)b * OUTD + t] = a;
}

extern "C" void kernel_launch(void* const* d_in, const int* in_sizes, int n_in,
                              void* d_out, int out_size, void* d_ws, size_t ws_size,
                              hipStream_t stream) {
    const float* feats = (const float*)d_in[0];
    const int*   ei    = (const int*)d_in[1];
    const float* nmask = (const float*)d_in[2];
    const float* emask = (const float*)d_in[3];
    const float* inW   = (const float*)d_in[4];
    const float* inb   = (const float*)d_in[5];
    const float* selfW = (const float*)d_in[6];
    const float* selfb = (const float*)d_in[7];
    const float* neighW= (const float*)d_in[8];
    const float* neighb= (const float*)d_in[9];
    const float* lng   = (const float*)d_in[10];
    const float* lnb   = (const float*)d_in[11];
    const float* W1    = (const float*)d_in[12];
    const float* b1    = (const float*)d_in[13];
    const float* W2    = (const float*)d_in[14];
    const float* b2    = (const float*)d_in[15];
    float* out = (float*)d_out;

    const size_t nxh = (size_t)NNODE * H;
    char* w = (char*)d_ws;
    unsigned short* xh = (unsigned short*)w;  w += nxh * 2;
    unsigned short* xl = (unsigned short*)w;  w += nxh * 2;
    unsigned short* nh = (unsigned short*)w;  w += nxh * 2;
    unsigned short* Bp = (unsigned short*)w;  w += (size_t)NLAYER * BPL * 2;
    float* part = (float*)w;                  w += (size_t)B * PCHUNK * (2 * H + 1) * 4;
    int* cnt_i  = (int*)w;                    w += (size_t)NNODE * 4;
    int* off    = (int*)w;                    w += ((size_t)NNODE + 4) * 4;
    int* cur    = (int*)w;                    w += (size_t)NNODE * 4;
    int* esrc   = (int*)w;                    w += (size_t)B * E * 4;
    float* emv  = (float*)w;

    k_prepB<<<NLAYER * KSTEPS * 8, 64, 0, stream>>>(selfW, neighW, Bp);
    k_inproj3<<<NNODE / TM, 256, 0, stream>>>(feats, inW, inb, xh, xl);

    hipMemsetAsync(cnt_i, 0, (size_t)NNODE * sizeof(int), stream);
    k_count<<<B * E / 256, 256, 0, stream>>>(ei, emask, cnt_i);
    k_scan<<<1, 1024, 0, stream>>>(cnt_i, off, cur);
    k_fill<<<B * E / 256, 256, 0, stream>>>(ei, emask, cur, esrc, emv);

    for (int l = 0; l < NLAYER; ++l) {
        k_gather3<<<NNODE / 4, 256, 0, stream>>>((const unsigned int*)xh, off, esrc, emv,
                                                 (unsigned int*)nh);
        k_layer4<<<NNODE / 32, 256, 0, stream>>>(xh, xl, nh,
                                                 Bp + (size_t)l * BPL,
                                                 selfb + (size_t)l * H, neighb + (size_t)l * H,
                                                 lng + (size_t)l * H, lnb + (size_t)l * H,
                                                 nmask, xh, xl);
    }

    k_pool1<<<dim3(B, PCHUNK), H, 0, stream>>>(xh, xl, nmask, part);
    k_tail<<<B, 256, 0, stream>>>(part, W1, b1, W2, b2, out);
}

// Round 7
// 429.071 us; speedup vs baseline: 1.1091x; 1.1091x over previous
//
#include <hip/hip_runtime.h>
#include <hip/hip_bf16.h>

#define B 8
#define N 8192
#define E 65536
#define FIN 64
#define H 128
#define OUTD 256
#define NLAYER 3
#define EPS 1e-5f
#define PCHUNK 64
#define PNODES (N / PCHUNK)
#define TM 32
#define PADF 68
#define NNODE (B * N)            // 65536 rows
#define KSTEPS 16                // 4 groups x 4 k-steps of K=32
#define BPL (KSTEPS * 8 * 512)   // Bp ushort elems per layer

typedef float f32x4 __attribute__((ext_vector_type(4)));
typedef __bf16 bf16x8 __attribute__((ext_vector_type(8)));

__device__ __forceinline__ float b2f(unsigned short u) {
    union { float f; unsigned int i; } c; c.i = ((unsigned int)u) << 16; return c.f;
}
__device__ __forceinline__ unsigned short f2b(float f) {
    __hip_bfloat16 h = __float2bfloat16(f);          // RTNE
    return *reinterpret_cast<unsigned short*>(&h);
}

// ---------------- weight pre-pack: fragment-ordered split-bf16 B' ----------------
// groups: 0 xh*sWhi, 1 xl*sWhi, 2 xh*sWlo, 3 nh*nWhi
__global__ void k_prepB(const float* __restrict__ selfW, const float* __restrict__ neighW,
                        unsigned short* __restrict__ Bp) {
    const int idx = blockIdx.x;            // l*KSTEPS*8 + s*8 + t
    const int t = idx & 7;
    const int s = (idx >> 3) % KSTEPS;
    const int l = idx / (KSTEPS * 8);
    const int lane = threadIdx.x;
    const int quad = lane >> 4, col = lane & 15;
    const int g = s >> 2;
    const float* W = ((g < 3) ? selfW : neighW) + (size_t)l * H * H;
    const bool lo = (g == 2);
    const int n = t * 16 + col;
    unsigned short* dst = Bp + ((size_t)(l * KSTEPS + s) * 8 + t) * 512 + lane * 8;
    #pragma unroll
    for (int j = 0; j < 8; ++j) {
        const int kk = (s & 3) * 32 + quad * 8 + j;
        const float w = W[kk * H + n];
        const unsigned short hi = f2b(w);
        dst[j] = lo ? f2b(w - b2f(hi)) : hi;
    }
}

// ---------------- input projection -> split-bf16 x ----------------
__global__ __launch_bounds__(256) void k_inproj3(const float* __restrict__ feats,
                                                 const float* __restrict__ W,
                                                 const float* __restrict__ bias,
                                                 unsigned short* __restrict__ xh,
                                                 unsigned short* __restrict__ xl) {
    __shared__ float fs[TM * PADF];
    __shared__ float wB[FIN * H];
    const int tid = threadIdx.x;
    const int i = tid >> 5, j = tid & 31;
    const int row0 = blockIdx.x * TM;

    for (int v = tid; v < TM * (FIN / 4); v += 256) {
        int n = v >> 4, kq = (v & 15) << 2;
        *(float4*)&fs[n * PADF + kq] = *(const float4*)&feats[(size_t)(row0 + n) * FIN + kq];
    }
    for (int v = tid; v < FIN * H / 4; v += 256)
        *(float4*)&wB[v * 4] = *(const float4*)&W[v * 4];
    __syncthreads();

    float acc[4][4] = {};
    #pragma unroll
    for (int k4 = 0; k4 < FIN / 4; ++k4) {
        float4 xa[4];
        #pragma unroll
        for (int a = 0; a < 4; ++a)
            xa[a] = *(const float4*)&fs[(i * 4 + a) * PADF + k4 * 4];
        #pragma unroll
        for (int t = 0; t < 4; ++t) {
            float4 bs = *(const float4*)&wB[(k4 * 4 + t) * H + (j << 2)];
            #pragma unroll
            for (int a = 0; a < 4; ++a) {
                const float va = ((const float*)&xa[a])[t];
                acc[a][0] = fmaf(va, bs.x, acc[a][0]);
                acc[a][1] = fmaf(va, bs.y, acc[a][1]);
                acc[a][2] = fmaf(va, bs.z, acc[a][2]);
                acc[a][3] = fmaf(va, bs.w, acc[a][3]);
            }
        }
    }
    const float4 bv = *(const float4*)&bias[j << 2];
    #pragma unroll
    for (int a = 0; a < 4; ++a) {
        float o[4];
        o[0] = fmaxf(acc[a][0] + bv.x, 0.f);
        o[1] = fmaxf(acc[a][1] + bv.y, 0.f);
        o[2] = fmaxf(acc[a][2] + bv.z, 0.f);
        o[3] = fmaxf(acc[a][3] + bv.w, 0.f);
        ushort4 h4, l4;
        h4.x = f2b(o[0]); l4.x = f2b(o[0] - b2f(h4.x));
        h4.y = f2b(o[1]); l4.y = f2b(o[1] - b2f(h4.y));
        h4.z = f2b(o[2]); l4.z = f2b(o[2] - b2f(h4.z));
        h4.w = f2b(o[3]); l4.w = f2b(o[3] - b2f(h4.w));
        const size_t a0 = (size_t)(row0 + i * 4 + a) * H + (j << 2);
        *(ushort4*)&xh[a0] = h4;
        *(ushort4*)&xl[a0] = l4;
    }
}

// ---------------- CSR build ----------------
__global__ void k_count(const int* __restrict__ ei, const float* __restrict__ emask,
                        int* __restrict__ cnt_i) {
    const int ge = blockIdx.x * 256 + threadIdx.x;
    if (emask[ge] > 0.f) {
        const int b = ge >> 16, e = ge & 0xFFFF;
        const int tgt = ei[(b * 2 + 1) * E + e];
        atomicAdd(&cnt_i[b * N + tgt], 1);
    }
}

__global__ __launch_bounds__(1024) void k_scan(const int* __restrict__ cnt_i,
                                               int* __restrict__ off, int* __restrict__ cur) {
    __shared__ int part[1024];
    const int t = threadIdx.x;
    const int base = t * 64;
    int s = 0;
    const int4* c4 = (const int4*)(cnt_i + base);
    #pragma unroll
    for (int u = 0; u < 16; ++u) {
        const int4 v = c4[u];
        s += v.x + v.y + v.z + v.w;
    }
    part[t] = s;
    __syncthreads();
    for (int d = 1; d < 1024; d <<= 1) {
        int v = (t >= d) ? part[t - d] : 0;
        __syncthreads();
        part[t] += v;
        __syncthreads();
    }
    int pre = (t == 0) ? 0 : part[t - 1];
    for (int u = 0; u < 64; ++u) {
        const int c = cnt_i[base + u];
        off[base + u] = pre;
        cur[base + u] = pre;
        pre += c;
    }
    if (t == 1023) off[NNODE] = pre;
}

__global__ void k_fill(const int* __restrict__ ei, const float* __restrict__ emask,
                       int* __restrict__ cur, int* __restrict__ esrc, float* __restrict__ emv) {
    const int ge = blockIdx.x * 256 + threadIdx.x;
    const float m = emask[ge];
    if (m > 0.f) {
        const int b = ge >> 16, e = ge & 0xFFFF;
        const int tgt = ei[(b * 2 + 1) * E + e];
        const int src = ei[(b * 2) * E + e];
        const int p = atomicAdd(&cur[b * N + tgt], 1);
        esrc[p] = b * N + src;
        emv[p] = m;
    }
}

// ---------------- gather: mean over incoming edges, bf16-hi input, wave-per-row ----------------
// XCD swizzle: batch = blockIdx & 7 pins each batch's slice to one XCD's L2.
__global__ __launch_bounds__(256) void k_gather3(const unsigned int* __restrict__ xh32,
                                                 const int* __restrict__ off,
                                                 const int* __restrict__ esrc,
                                                 const float* __restrict__ emv,
                                                 unsigned int* __restrict__ nh32) {
    const int beta = blockIdx.x;               // 0..16383
    const int b = beta & 7;
    const int grp = beta >> 3;                 // 0..2047
    const int wave = threadIdx.x >> 6, lane = threadIdx.x & 63;
    const int r = b * N + grp * 4 + wave;
    const int j0 = off[r], j1 = off[r + 1];
    float a0 = 0.f, a1 = 0.f, c = 0.f;
    for (int base = j0; base < j1; base += 64) {
        const int myj = base + lane;
        int s_l = 0; float m_l = 0.f;
        if (myj < j1) { s_l = esrc[myj]; m_l = emv[myj]; }
        const int cnt = min(64, j1 - base);
        #pragma unroll 4
        for (int jj = 0; jj < cnt; ++jj) {
            const int src = __shfl(s_l, jj);
            const float m = __shfl(m_l, jj);
            const unsigned int u = xh32[(size_t)src * 64 + lane];
            union { unsigned int i; float f; } lo, hi;
            lo.i = u << 16;
            hi.i = u & 0xFFFF0000u;
            a0 = fmaf(lo.f, m, a0);
            a1 = fmaf(hi.f, m, a1);
            c += m;
        }
    }
    const float inv = 1.f / fmaxf(c, 1.f);
    nh32[(size_t)r * 64 + lane] = (unsigned int)f2b(a0 * inv) | ((unsigned int)f2b(a1 * inv) << 16);
}

// ---------------- fused layer v5: 64 rows/block, batch<->XCD aligned, 2 m-tiles/wave ----------------
// 1024 blocks x 256 threads (4 waves). wave w: mg=w>>1 (m-tiles mg*2, mg*2+1), nw=w&1 (n-tiles nw*4..+3).
// acc[2][4]; depth-1 prefetch; per-step: 2 A-loads + 4 B-loads -> 8 MFMAs.
__global__ __launch_bounds__(256) void k_layer5(const unsigned short* __restrict__ xh,
                                                const unsigned short* __restrict__ xl,
                                                const unsigned short* __restrict__ nh,
                                                const unsigned short* __restrict__ Bp,
                                                const float* __restrict__ sb,
                                                const float* __restrict__ nb,
                                                const float* __restrict__ lng,
                                                const float* __restrict__ lnb,
                                                const float* __restrict__ nmask,
                                                unsigned short* __restrict__ oxh,
                                                unsigned short* __restrict__ oxl) {
    const int tid = threadIdx.x;
    const int wave = tid >> 6, lane = tid & 63;
    const int quad = lane >> 4, col = lane & 15;
    const int mg = wave >> 1, nw = wave & 1;
    const int u = blockIdx.x;
    const int b = u & 7;
    const int row0 = b * N + (u >> 3) * 64;       // batch-pinned to XCD b

    size_t abase[2];
    #pragma unroll
    for (int mt = 0; mt < 2; ++mt)
        abase[mt] = (size_t)(row0 + (mg * 2 + mt) * 16 + col) * H + quad * 8;

    f32x4 acc[2][4] = {};

    // prefetch step 0 (group 0 = xh)
    bf16x8 aC[2], bC[4];
    #pragma unroll
    for (int mt = 0; mt < 2; ++mt) aC[mt] = *(const bf16x8*)&xh[abase[mt]];
    #pragma unroll
    for (int nt = 0; nt < 4; ++nt)
        bC[nt] = *(const bf16x8*)&Bp[((size_t)(nw * 4 + nt)) * 512 + lane * 8];

    #pragma unroll
    for (int s = 0; s < KSTEPS; ++s) {
        bf16x8 aN[2], bN[4];
        if (s + 1 < KSTEPS) {
            const int s1 = s + 1, g1 = s1 >> 2;
            const unsigned short* A = (g1 == 0 || g1 == 2) ? xh : (g1 == 1) ? xl : nh;
            const int ko = (s1 & 3) * 32;
            #pragma unroll
            for (int mt = 0; mt < 2; ++mt) aN[mt] = *(const bf16x8*)&A[abase[mt] + ko];
            #pragma unroll
            for (int nt = 0; nt < 4; ++nt)
                bN[nt] = *(const bf16x8*)&Bp[((size_t)s1 * 8 + nw * 4 + nt) * 512 + lane * 8];
        }
        #pragma unroll
        for (int mt = 0; mt < 2; ++mt)
            #pragma unroll
            for (int nt = 0; nt < 4; ++nt)
                acc[mt][nt] = __builtin_amdgcn_mfma_f32_16x16x32_bf16(aC[mt], bC[nt], acc[mt][nt], 0, 0, 0);
        #pragma unroll
        for (int mt = 0; mt < 2; ++mt) aC[mt] = aN[mt];
        #pragma unroll
        for (int nt = 0; nt < 4; ++nt) bC[nt] = bN[nt];
    }

    // bias + relu (C/D: row = quad*4 + r, col = lane&15; h = (nw*4+nt)*16 + col)
    float sbv[4], nbv[4], gv[4], bbv[4];
    #pragma unroll
    for (int nt = 0; nt < 4; ++nt) {
        const int hh = (nw * 4 + nt) * 16 + col;
        sbv[nt] = sb[hh]; nbv[nt] = nb[hh]; gv[nt] = lng[hh]; bbv[nt] = lnb[hh];
    }
    #pragma unroll
    for (int mt = 0; mt < 2; ++mt)
        #pragma unroll
        for (int nt = 0; nt < 4; ++nt)
            #pragma unroll
            for (int r = 0; r < 4; ++r)
                acc[mt][nt][r] = fmaxf(acc[mt][nt][r] + sbv[nt] + nbv[nt], 0.f);

    // LN partials: wave covers 64 of 128 h for its 32 rows
    __shared__ float lsum[2][64];
    __shared__ float lsq[2][64];
    #pragma unroll
    for (int mt = 0; mt < 2; ++mt)
        #pragma unroll
        for (int r = 0; r < 4; ++r) {
            float p = 0.f, q = 0.f;
            #pragma unroll
            for (int nt = 0; nt < 4; ++nt) {
                const float v = acc[mt][nt][r];
                p += v;
                q = fmaf(v, v, q);
            }
            p += __shfl_xor(p, 1);  q += __shfl_xor(q, 1);
            p += __shfl_xor(p, 2);  q += __shfl_xor(q, 2);
            p += __shfl_xor(p, 4);  q += __shfl_xor(q, 4);
            p += __shfl_xor(p, 8);  q += __shfl_xor(q, 8);
            if (col == 0) {
                const int rib = (mg * 2 + mt) * 16 + quad * 4 + r;
                lsum[nw][rib] = p;
                lsq[nw][rib] = q;
            }
        }
    __syncthreads();   // all A-reads done before in-place stores

    #pragma unroll
    for (int mt = 0; mt < 2; ++mt)
        #pragma unroll
        for (int r = 0; r < 4; ++r) {
            const int rib = (mg * 2 + mt) * 16 + quad * 4 + r;
            const int node = row0 + rib;
            const float mu = (lsum[0][rib] + lsum[1][rib]) * (1.f / H);
            const float var = (lsq[0][rib] + lsq[1][rib]) * (1.f / H) - mu * mu;
            const float isd = rsqrtf(var + EPS);
            const float m = nmask[node];
            #pragma unroll
            for (int nt = 0; nt < 4; ++nt) {
                const float y = (fmaf(acc[mt][nt][r] - mu, isd * gv[nt], bbv[nt])) * m;
                const unsigned short hi = f2b(y);
                const size_t a = (size_t)node * H + (nw * 4 + nt) * 16 + col;
                oxh[a] = hi;
                oxl[a] = f2b(y - b2f(hi));
            }
        }
}

// ---------------- pooling partials (xh only; 2^-9 rel error, fine) ----------------
__global__ void k_pool1(const unsigned short* __restrict__ xh,
                        const float* __restrict__ nmask, float* __restrict__ part) {
    const int b = blockIdx.x, c = blockIdx.y, h = threadIdx.x;
    const int n0 = c * PNODES;
    float s = 0.f, mx = -INFINITY, nv = 0.f;
    for (int it = 0; it < PNODES; ++it) {
        const int n = n0 + it;
        const float m = nmask[b * N + n];
        const float v = b2f(xh[((size_t)b * N + n) * H + h]) * m;
        s += v;
        if (m > 0.f) mx = fmaxf(mx, v);
        nv += m;
    }
    float* p = part + ((size_t)b * PCHUNK + c) * (2 * H + 1);
    p[h] = s;
    p[H + h] = mx;
    if (h == 0) p[2 * H] = nv;
}

// ---------------- fused pool-reduce + MLP head ----------------
__global__ __launch_bounds__(256) void k_tail(const float* __restrict__ part,
                                              const float* __restrict__ W1, const float* __restrict__ b1,
                                              const float* __restrict__ W2, const float* __restrict__ b2,
                                              float* __restrict__ out) {
    const int b = blockIdx.x, t = threadIdx.x;
    __shared__ float g[2 * H];
    __shared__ float hid[H];
    {
        float nv = 0.f;
        for (int c = 0; c < PCHUNK; ++c)
            nv += part[((size_t)b * PCHUNK + c) * (2 * H + 1) + 2 * H];
        if (t < H) {
            float s = 0.f;
            for (int c = 0; c < PCHUNK; ++c)
                s += part[((size_t)b * PCHUNK + c) * (2 * H + 1) + t];
            g[t] = s / fmaxf(nv, 1.f);
        } else {
            const int h = t - H;
            float mx = -INFINITY;
            for (int c = 0; c < PCHUNK; ++c)
                mx = fmaxf(mx, part[((size_t)b * PCHUNK + c) * (2 * H + 1) + H + h]);
            g[t] = mx;
        }
    }
    __syncthreads();
    if (t < H) {
        float a = b1[t];
        #pragma unroll 8
        for (int k = 0; k < 2 * H; ++k) a = fmaf(g[k], W1[k * H + t], a);
        hid[t] = fmaxf(a, 0.f);
    }
    __syncthreads();
    float a = b2[t];
    #pragma unroll 8
    for (int k = 0; k < H; ++k) a = fmaf(hid[k], W2[k * OUTD + t], a);
    out[(size_t)b * OUTD + t] = a;
}

extern "C" void kernel_launch(void* const* d_in, const int* in_sizes, int n_in,
                              void* d_out, int out_size, void* d_ws, size_t ws_size,
                              hipStream_t stream) {
    const float* feats = (const float*)d_in[0];
    const int*   ei    = (const int*)d_in[1];
    const float* nmask = (const float*)d_in[2];
    const float* emask = (const float*)d_in[3];
    const float* inW   = (const float*)d_in[4];
    const float* inb   = (const float*)d_in[5];
    const float* selfW = (const float*)d_in[6];
    const float* selfb = (const float*)d_in[7];
    const float* neighW= (const float*)d_in[8];
    const float* neighb= (const float*)d_in[9];
    const float* lng   = (const float*)d_in[10];
    const float* lnb   = (const float*)d_in[11];
    const float* W1    = (const float*)d_in[12];
    const float* b1    = (const float*)d_in[13];
    const float* W2    = (const float*)d_in[14];
    const float* b2    = (const float*)d_in[15];
    float* out = (float*)d_out;

    const size_t nxh = (size_t)NNODE * H;
    char* w = (char*)d_ws;
    unsigned short* xh = (unsigned short*)w;  w += nxh * 2;
    unsigned short* xl = (unsigned short*)w;  w += nxh * 2;
    unsigned short* nh = (unsigned short*)w;  w += nxh * 2;
    unsigned short* Bp = (unsigned short*)w;  w += (size_t)NLAYER * BPL * 2;
    float* part = (float*)w;                  w += (size_t)B * PCHUNK * (2 * H + 1) * 4;
    int* cnt_i  = (int*)w;                    w += (size_t)NNODE * 4;
    int* off    = (int*)w;                    w += ((size_t)NNODE + 4) * 4;
    int* cur    = (int*)w;                    w += (size_t)NNODE * 4;
    int* esrc   = (int*)w;                    w += (size_t)B * E * 4;
    float* emv  = (float*)w;

    k_prepB<<<NLAYER * KSTEPS * 8, 64, 0, stream>>>(selfW, neighW, Bp);
    k_inproj3<<<NNODE / TM, 256, 0, stream>>>(feats, inW, inb, xh, xl);

    hipMemsetAsync(cnt_i, 0, (size_t)NNODE * sizeof(int), stream);
    k_count<<<B * E / 256, 256, 0, stream>>>(ei, emask, cnt_i);
    k_scan<<<1, 1024, 0, stream>>>(cnt_i, off, cur);
    k_fill<<<B * E / 256, 256, 0, stream>>>(ei, emask, cur, esrc, emv);

    for (int l = 0; l < NLAYER; ++l) {
        k_gather3<<<NNODE / 4, 256, 0, stream>>>((const unsigned int*)xh, off, esrc, emv,
                                                 (unsigned int*)nh);
        k_layer5<<<NNODE / 64, 256, 0, stream>>>(xh, xl, nh,
                                                 Bp + (size_t)l * BPL,
                                                 selfb + (size_t)l * H, neighb + (size_t)l * H,
                                                 lng + (size_t)l * H, lnb + (size_t)l * H,
                                                 nmask, xh, xl);
    }

    k_pool1<<<dim3(B, PCHUNK), H, 0, stream>>>(xh, nmask, part);
    k_tail<<<B, 256, 0, stream>>>(part, W1, b1, W2, b2, out);
}